// Round 5
// baseline (3507.788 us; speedup 1.0000x reference)
//
#include <hip/hip_runtime.h>
#include <math.h>

#define DIM  1024
#define SEQ  64
#define HDIM 256
#define NBLK 256

// ---------------- wave / block reduction helpers ----------------
__device__ __forceinline__ float wsum(float v){
  v += __shfl_xor(v, 32, 64); v += __shfl_xor(v, 16, 64); v += __shfl_xor(v, 8, 64);
  v += __shfl_xor(v, 4, 64);  v += __shfl_xor(v, 2, 64);  v += __shfl_xor(v, 1, 64);
  return v;
}
__device__ __forceinline__ float wmax(float v){
  v = fmaxf(v, __shfl_xor(v, 32, 64)); v = fmaxf(v, __shfl_xor(v, 16, 64));
  v = fmaxf(v, __shfl_xor(v, 8, 64));  v = fmaxf(v, __shfl_xor(v, 4, 64));
  v = fmaxf(v, __shfl_xor(v, 2, 64));  v = fmaxf(v, __shfl_xor(v, 1, 64));
  return v;
}
__device__ __forceinline__ float breduce(float v, float* red){
  int tid = threadIdx.x;
  v = wsum(v);
  if ((tid & 63) == 0) red[tid >> 6] = v;
  __syncthreads();
  float r = red[0] + red[1] + red[2] + red[3];
  __syncthreads();
  return r;
}

// ---------------- device-coherent (cross-XCD) payload access ----------------
// relaxed agent atomics carry the sc-bits that bypass L1/L2 to the LLC
__device__ __forceinline__ float ldc(const float* p){
  return __hip_atomic_load(p, __ATOMIC_RELAXED, __HIP_MEMORY_SCOPE_AGENT);
}
__device__ __forceinline__ void stc(float* p, float v){
  __hip_atomic_store(p, v, __ATOMIC_RELAXED, __HIP_MEMORY_SCOPE_AGENT);
}

// ---- fence-free flat barrier ----
// All cross-block payloads go through stc/ldc (LLC-coherent), so no cache
// maintenance (release wbl2 / acquire inv) is needed — only "payload stores
// drained before slot store", which vmcnt(0)+__syncthreads provides.
// Every thread t polls slot[t] directly: one LLC round trip on the critical path.
__device__ __forceinline__ void gsync(unsigned* slots, unsigned ep, int bid, int tid){
  asm volatile("s_waitcnt vmcnt(0)" ::: "memory");
  __syncthreads();
  if (tid == 0)
    __hip_atomic_store(&slots[bid], ep, __ATOMIC_RELAXED, __HIP_MEMORY_SCOPE_AGENT);
  {
    unsigned spins = 0;
    while (__hip_atomic_load(&slots[tid], __ATOMIC_RELAXED, __HIP_MEMORY_SCOPE_AGENT) < ep){
      if (++spins > 4194304u){
        unsigned s2 = 0;   // acquire fallback: livelock-proof, never taken normally
        while (__hip_atomic_load(&slots[tid], __ATOMIC_ACQUIRE, __HIP_MEMORY_SCOPE_AGENT) < ep){
          __builtin_amdgcn_s_sleep(2);
          if (++s2 > 100000000u) break;
        }
        break;
      }
    }
  }
  __syncthreads();
  asm volatile("" ::: "memory");
}

// ---------------- precompute kernels ----------------
__global__ void pe_kernel(float* pe){
  int t = blockIdx.x;
  int pos = t % 30;
  for (int d = threadIdx.x; d < DIM; d += 256){
    int m = d >> 1;
    float div = __expf((float)(2 * m) * (-9.210340371976184f / 1024.0f));
    float arg = (float)pos * div;
    pe[t * DIM + d] = (d & 1) ? cosf(arg) : sinf(arg);
  }
}

__global__ void gemv_rows(const float* __restrict__ X, const float* __restrict__ W,
                          const float* __restrict__ b, float* __restrict__ Y,
                          int K, int R){
  int t = blockIdx.y;
  int r = blockIdx.x * 4 + (threadIdx.x >> 6);
  int lane = threadIdx.x & 63;
  const float* x  = X + (size_t)t * K;
  const float* wr = W + (size_t)r * K;
  float acc = 0.f;
  for (int d = lane; d < K; d += 64) acc = fmaf(wr[d], x[d], acc);
  acc = wsum(acc);
  if (lane == 0) Y[(size_t)t * R + r] = acc + b[r];
}

__global__ void matmul_nn_1024(const float* __restrict__ A, const float* __restrict__ B,
                               float* __restrict__ Cc){
  __shared__ float As[32][33];
  __shared__ float Bs[32][33];
  int tb = blockIdx.x * 32, ta = blockIdx.y * 32;
  int tx = threadIdx.x & 31, ty = threadIdx.x >> 5;
  float acc[4] = {0.f, 0.f, 0.f, 0.f};
  for (int k0 = 0; k0 < 1024; k0 += 32){
    for (int r = ty; r < 32; r += 8) As[r][tx] = A[(size_t)(ta + r) * 1024 + k0 + tx];
    for (int r = ty; r < 32; r += 8) Bs[r][tx] = B[(size_t)(k0 + r) * 1024 + tb + tx];
    __syncthreads();
    #pragma unroll
    for (int kk = 0; kk < 32; ++kk){
      float bv = Bs[kk][tx];
      #pragma unroll
      for (int m = 0; m < 4; ++m) acc[m] = fmaf(As[ty + 8 * m][kk], bv, acc[m]);
    }
    __syncthreads();
  }
  for (int m = 0; m < 4; ++m) Cc[(size_t)(ta + ty + 8 * m) * 1024 + tb + tx] = acc[m];
}

__global__ void cb_kernel(const float* __restrict__ vm_w, const float* __restrict__ vr_b,
                          const float* __restrict__ vm_b, const float* __restrict__ obj_w,
                          float* __restrict__ cb){
  int gw = blockIdx.x * 4 + (threadIdx.x >> 6);
  int lane = threadIdx.x & 63;
  const float* wr = vm_w + (size_t)gw * DIM;
  float acc = 0.f;
  for (int d = lane; d < DIM; d += 64) acc = fmaf(wr[d], vr_b[d], acc);
  acc = wsum(acc);
  if (lane == 0) cb[gw] = acc + vm_b[gw] + obj_w[(size_t)gw * 80];
}

// ---------------- the persistent autoregressive decode ----------------
struct CoopArgs {
  const float *sa_in_w, *sa_in_b, *sa_out_w, *sa_out_b;
  const float *ln1_g, *ln1_b, *ln2_g, *ln2_b, *ln3_g, *ln3_b;
  const float *ff1_w, *ff1_b, *ff2_w, *ff2_b;
  const float *vr_w, *vr_b, *obj_w;
  const float *pe, *cac, *Cm, *cb;
  float *emb, *kct, *vc, *q, *u, *hb, *w;
  float *out;
  unsigned *bar;   // slots[256]
};

__global__ void __launch_bounds__(256, 2) decode_loop(CoopArgs a){
  const int tid = threadIdx.x, bid = blockIdx.x;
  const int wave = tid >> 6, lane = tid & 63;
  const int gw = bid * 4 + wave;            // global wave id / output row, 0..1023
  __shared__ float sm[2048];
  __shared__ float scp[256];                // softmax probs [head][64]
  __shared__ float red[8];
  unsigned* slots = a.bar;
  unsigned ep = 0;

  // ---- preload this wave's hot weight rows (128 floats/thread -> VGPR/AGPR)
  float wq[16], wk[16], wv[16], wo[16], f1a[16], f1b[16], f2[32];
  {
    const float* pq = a.sa_in_w + (size_t)gw * DIM;
    const float* pk = a.sa_in_w + (size_t)(DIM + gw) * DIM;
    const float* pv = a.sa_in_w + (size_t)(2 * DIM + gw) * DIM;
    const float* po = a.sa_out_w + (size_t)gw * DIM;
    const float* p1a = a.ff1_w + (size_t)(2 * gw) * DIM;
    const float* p1b = a.ff1_w + (size_t)(2 * gw + 1) * DIM;
    const float* p2 = a.ff2_w + (size_t)gw * 2048;
    #pragma unroll
    for (int k = 0; k < 16; ++k){
      int d = lane + 64 * k;
      wq[k] = pq[d]; wk[k] = pk[d]; wv[k] = pv[d]; wo[k] = po[d];
      f1a[k] = p1a[d]; f1b[k] = p1b[d];
    }
    #pragma unroll
    for (int k = 0; k < 32; ++k) f2[k] = p2[lane + 64 * k];
  }
  // per-row bias scalars (constant across iterations)
  const float b_q  = a.sa_in_b[gw];
  const float b_k  = a.sa_in_b[DIM + gw];
  const float b_v  = a.sa_in_b[2 * DIM + gw];
  const float b_o  = a.sa_out_b[gw];
  const float b_1a = a.ff1_b[2 * gw];
  const float b_1b = a.ff1_b[2 * gw + 1];
  const float b_2  = a.ff2_b[gw];
  const float b_vr = a.vr_b[gw];

  // S0: emb row 0 = style
  if (bid == 0){
    for (int d = tid; d < DIM; d += 256) stc(a.emb + d, a.obj_w[(size_t)d * 80]);
  }
  ++ep; gsync(slots, ep, bid, tid);
  const float cbv = a.cb[gw];   // cb written by prologue kernel (stream-ordered)

  for (int i = 0; i < SEQ; ++i){
    const float* per = a.pe + i * DIM;

    // ---- S1: QKV gemv; fill KV cache row i (kct transposed: [dim][64])
    {
      float* xs = sm;
      const float* er = a.emb + (size_t)i * DIM;
      for (int t = tid; t < DIM; t += 256) xs[t] = ldc(er + t) + per[t];
      __syncthreads();
      float aq = 0.f, ak = 0.f, av = 0.f;
      #pragma unroll
      for (int k = 0; k < 16; ++k){
        float x = xs[lane + 64 * k];
        aq = fmaf(wq[k], x, aq);
        ak = fmaf(wk[k], x, ak);
        av = fmaf(wv[k], x, av);
      }
      aq = wsum(aq); ak = wsum(ak); av = wsum(av);
      if (lane == 0){
        stc(a.q + gw, aq + b_q);
        stc(a.kct + (size_t)gw * 64 + i, ak + b_k);
        stc(a.vc + (size_t)i * DIM + gw, av + b_v);
      }
      __syncthreads();
    }
    ++ep; gsync(slots, ep, bid, tid);

    // ---- S2: full attention (all blocks, redundant) + out-proj row gw -> u
    {
      float* qs = sm;   // 1024; reused as os after scores are done
      for (int t = tid; t < DIM; t += 256) qs[t] = ldc(a.q + t);
      __syncthreads();
      // scores: wave = head, lane = key index j
      const int h = wave;
      float s;
      if (lane <= i){
        const float* kp = a.kct + ((size_t)h * 256) * 64 + lane;
        float acc = 0.f;
        #pragma unroll 8
        for (int d = 0; d < 256; ++d) acc = fmaf(qs[h * 256 + d], ldc(kp + d * 64), acc);
        float slope = 1.0f / (float)(4 << (2 * h));   // 0.25^(h+1)
        s = acc * 0.0625f - slope * (float)((i - lane) / 30);
      } else {
        s = -3.0e38f;
      }
      float mx = wmax(s);
      float p = (lane <= i) ? __expf(s - mx) : 0.f;
      float sum = wsum(p);
      scp[h * 64 + lane] = p / sum;
      __syncthreads();
      // PV: thread owns dims tid+256m (head m); o into os (= sm, qs dead)
      float o0 = 0.f, o1 = 0.f, o2 = 0.f, o3 = 0.f;
      for (int j = 0; j <= i; ++j){
        const float* vrow = a.vc + (size_t)j * DIM;
        float p0 = scp[j], p1 = scp[64 + j], p2 = scp[128 + j], p3 = scp[192 + j];
        o0 = fmaf(p0, ldc(vrow + tid), o0);
        o1 = fmaf(p1, ldc(vrow + 256 + tid), o1);
        o2 = fmaf(p2, ldc(vrow + 512 + tid), o2);
        o3 = fmaf(p3, ldc(vrow + 768 + tid), o3);
      }
      __syncthreads();
      float* os = sm;
      os[tid] = o0; os[tid + 256] = o1; os[tid + 512] = o2; os[tid + 768] = o3;
      __syncthreads();
      // out-proj row gw + residual
      float acc = 0.f;
      #pragma unroll
      for (int k = 0; k < 16; ++k) acc = fmaf(wo[k], os[lane + 64 * k], acc);
      acc = wsum(acc);
      if (lane == 0){
        float x = ldc(a.emb + (size_t)i * DIM + gw) + per[gw];
        stc(a.u + gw, x + acc + b_o);
      }
      __syncthreads();
    }
    ++ep; gsync(slots, ep, bid, tid);

    // ---- S3: ln1 -> +ca_contrib -> ln2 (local) ; ff1 rows -> hb
    float x2v;
    {
      float* xs = sm;
      for (int t = tid; t < DIM; t += 256) xs[t] = ldc(a.u + t);
      __syncthreads();
      float s0 = 0.f;
      #pragma unroll
      for (int k = 0; k < 4; ++k) s0 += xs[tid + 256 * k];
      float mean = breduce(s0, red) * (1.f / 1024.f);
      float s1 = 0.f;
      #pragma unroll
      for (int k = 0; k < 4; ++k){ float dd = xs[tid + 256 * k] - mean; s1 = fmaf(dd, dd, s1); }
      float var = breduce(s1, red) * (1.f / 1024.f);
      float rs = 1.f / sqrtf(var + 1e-5f);
      float tv[4];
      #pragma unroll
      for (int k = 0; k < 4; ++k){
        int d = tid + 256 * k;
        float x1 = (xs[d] - mean) * rs * a.ln1_g[d] + a.ln1_b[d];
        tv[k] = x1 + a.cac[(size_t)i * DIM + d];
      }
      float t0 = tv[0] + tv[1] + tv[2] + tv[3];
      float mean2 = breduce(t0, red) * (1.f / 1024.f);
      float t1 = 0.f;
      #pragma unroll
      for (int k = 0; k < 4; ++k){ float dd = tv[k] - mean2; t1 = fmaf(dd, dd, t1); }
      float var2 = breduce(t1, red) * (1.f / 1024.f);
      float rs2 = 1.f / sqrtf(var2 + 1e-5f);
      #pragma unroll
      for (int k = 0; k < 4; ++k){
        int d = tid + 256 * k;
        xs[d] = (tv[k] - mean2) * rs2 * a.ln2_g[d] + a.ln2_b[d];
      }
      __syncthreads();
      x2v = xs[gw];   // this wave's x2 element, kept in-register for S4
      float acc0 = 0.f, acc1 = 0.f;
      #pragma unroll
      for (int k = 0; k < 16; ++k){
        float x = xs[lane + 64 * k];
        acc0 = fmaf(f1a[k], x, acc0);
        acc1 = fmaf(f1b[k], x, acc1);
      }
      acc0 = wsum(acc0); acc1 = wsum(acc1);
      if (lane == 0){
        stc(a.hb + 2 * gw,     fmaxf(acc0 + b_1a, 0.f));
        stc(a.hb + 2 * gw + 1, fmaxf(acc1 + b_1b, 0.f));
      }
      __syncthreads();
    }
    ++ep; gsync(slots, ep, bid, tid);

    // ---- S4: w = x2 + h @ ff2_w.T + b ; prefetch S5's vr_w/Cm rows into regs
    float vrr[16], cmr[16];
    {
      float* hsm = sm;
      for (int t = tid; t < 2048; t += 256) hsm[t] = ldc(a.hb + t);
      // prefetch (independent of hb; L2 latency hides under barrier wait)
      const float* pr = a.vr_w + (size_t)gw * DIM;
      const float* pc = a.Cm + (size_t)gw * DIM;
      #pragma unroll
      for (int k = 0; k < 16; ++k){ vrr[k] = pr[lane + 64 * k]; cmr[k] = pc[lane + 64 * k]; }
      __syncthreads();
      float acc = 0.f;
      #pragma unroll
      for (int k = 0; k < 32; ++k) acc = fmaf(f2[k], hsm[lane + 64 * k], acc);
      acc = wsum(acc);
      if (lane == 0) stc(a.w + gw, x2v + acc + b_2);
      __syncthreads();
    }
    ++ep; gsync(slots, ep, bid, tid);

    // ---- S5: ln3; final-output row i; recurrence new_tok -> emb[i+1]
    {
      float* xs = sm;
      for (int t = tid; t < DIM; t += 256) xs[t] = ldc(a.w + t);
      __syncthreads();
      float s0 = 0.f;
      #pragma unroll
      for (int k = 0; k < 4; ++k) s0 += xs[tid + 256 * k];
      float mean = breduce(s0, red) * (1.f / 1024.f);
      float s1 = 0.f;
      #pragma unroll
      for (int k = 0; k < 4; ++k){ float dd = xs[tid + 256 * k] - mean; s1 = fmaf(dd, dd, s1); }
      float var = breduce(s1, red) * (1.f / 1024.f);
      float rs = 1.f / sqrtf(var + 1e-5f);
      float ov[4];
      #pragma unroll
      for (int k = 0; k < 4; ++k){
        int d = tid + 256 * k;
        ov[k] = (xs[d] - mean) * rs * a.ln3_g[d] + a.ln3_b[d];
      }
      __syncthreads();
      #pragma unroll
      for (int k = 0; k < 4; ++k) xs[tid + 256 * k] = ov[k];
      __syncthreads();
      {
        float ar = 0.f, ac = 0.f;
        #pragma unroll
        for (int k = 0; k < 16; ++k){
          float x = xs[lane + 64 * k];
          ar = fmaf(vrr[k], x, ar);
          ac = fmaf(cmr[k], x, ac);
        }
        ar = wsum(ar); ac = wsum(ac);
        if (lane == 0){
          a.out[(size_t)i * DIM + gw] = ar + b_vr;
          if (i < SEQ - 1) stc(a.emb + (size_t)(i + 1) * DIM + gw, ac + cbv);
        }
      }
      __syncthreads();
    }
    ++ep; gsync(slots, ep, bid, tid);
  }
}

// ---------------- host launcher ----------------
extern "C" void kernel_launch(void* const* d_in, const int* in_sizes, int n_in,
                              void* d_out, int out_size, void* d_ws, size_t ws_size,
                              hipStream_t stream){
  const float* hs       = (const float*)d_in[0];
  const float* hid_w    = (const float*)d_in[1];
  const float* hid_b    = (const float*)d_in[2];
  const float* obj_w    = (const float*)d_in[3];
  const float* sa_in_w  = (const float*)d_in[4];
  const float* sa_in_b  = (const float*)d_in[5];
  const float* sa_out_w = (const float*)d_in[6];
  const float* sa_out_b = (const float*)d_in[7];
  const float* ca_in_w  = (const float*)d_in[8];
  const float* ca_in_b  = (const float*)d_in[9];
  const float* ca_out_w = (const float*)d_in[10];
  const float* ca_out_b = (const float*)d_in[11];
  const float* ln1_g    = (const float*)d_in[12];
  const float* ln1_b    = (const float*)d_in[13];
  const float* ln2_g    = (const float*)d_in[14];
  const float* ln2_b    = (const float*)d_in[15];
  const float* ln3_g    = (const float*)d_in[16];
  const float* ln3_b    = (const float*)d_in[17];
  const float* ff1_w    = (const float*)d_in[18];
  const float* ff1_b    = (const float*)d_in[19];
  const float* ff2_w    = (const float*)d_in[20];
  const float* ff2_b    = (const float*)d_in[21];
  const float* vr_w     = (const float*)d_in[22];
  const float* vr_b     = (const float*)d_in[23];
  const float* vm_w     = (const float*)d_in[24];
  const float* vm_b     = (const float*)d_in[25];

  float* ws = (float*)d_ws;
  float* pe   = ws;                 // 65536
  float* emb  = ws + 65536;         // 65536
  float* kct  = ws + 131072;        // 65536 (transposed: [dim][64])
  float* vc   = ws + 196608;        // 65536
  float* mem  = ws + 262144;        // 65536
  float* vtmp = ws + 327680;        // 65536
  float* cac  = ws + 393216;        // 65536
  float* Cm   = ws + 458752;        // 1048576
  float* q    = ws + 1507328;       // 1024
  float* u    = ws + 1508352;       // 1024
  float* hb   = ws + 1509376;       // 2048
  float* wv   = ws + 1511424;       // 1024
  float* cb   = ws + 1512448;       // 1024
  unsigned* bar = (unsigned*)(ws + 1513472);  // slots[256] (1KB, zeroed)

  hipMemsetAsync((void*)bar, 0, 4096, stream);

  pe_kernel<<<SEQ, 256, 0, stream>>>(pe);
  // mem = hs @ hid_w.T + hid_b
  gemv_rows<<<dim3(256, SEQ), 256, 0, stream>>>(hs, hid_w, hid_b, mem, 1024, 1024);
  // v = mem @ ca_wv.T + ca_bv   (cross-attention collapses to V)
  gemv_rows<<<dim3(256, SEQ), 256, 0, stream>>>(mem, ca_in_w + 2048 * 1024, ca_in_b + 2048, vtmp, 1024, 1024);
  // ca_contrib = v @ ca_out_w.T + ca_out_b
  gemv_rows<<<dim3(256, SEQ), 256, 0, stream>>>(vtmp, ca_out_w, ca_out_b, cac, 1024, 1024);
  // C = vm_w @ vr_w  (folds the two recurrence gemvs into one)
  matmul_nn_1024<<<dim3(32, 32), 256, 0, stream>>>(vm_w, vr_w, Cm);
  // cb = vm_w @ vr_b + vm_b + style
  cb_kernel<<<256, 256, 0, stream>>>(vm_w, vr_b, vm_b, obj_w, cb);

  CoopArgs A;
  A.sa_in_w = sa_in_w; A.sa_in_b = sa_in_b; A.sa_out_w = sa_out_w; A.sa_out_b = sa_out_b;
  A.ln1_g = ln1_g; A.ln1_b = ln1_b; A.ln2_g = ln2_g; A.ln2_b = ln2_b; A.ln3_g = ln3_g; A.ln3_b = ln3_b;
  A.ff1_w = ff1_w; A.ff1_b = ff1_b; A.ff2_w = ff2_w; A.ff2_b = ff2_b;
  A.vr_w = vr_w; A.vr_b = vr_b; A.obj_w = obj_w;
  A.pe = pe; A.cac = cac; A.Cm = Cm; A.cb = cb;
  A.emb = emb; A.kct = kct; A.vc = vc; A.q = q; A.u = u; A.hb = hb; A.w = wv;
  A.out = (float*)d_out;
  A.bar = bar;

  void* params[1] = { &A };
  hipError_t e = hipLaunchCooperativeKernel((void*)decode_loop, dim3(NBLK), dim3(256), params, 0, stream);
  if (e != hipSuccess){
    decode_loop<<<dim3(NBLK), dim3(256), 0, stream>>>(A);
  }
}

// Round 6
// 2328.469 us; speedup vs baseline: 1.5065x; 1.5065x over previous
//
#include <hip/hip_runtime.h>
#include <math.h>

#define DIM  1024
#define SEQ  64
#define HDIM 256
#define NBLK 256

// ---------------- wave / block reduction helpers ----------------
__device__ __forceinline__ float wsum(float v){
  v += __shfl_xor(v, 32, 64); v += __shfl_xor(v, 16, 64); v += __shfl_xor(v, 8, 64);
  v += __shfl_xor(v, 4, 64);  v += __shfl_xor(v, 2, 64);  v += __shfl_xor(v, 1, 64);
  return v;
}
__device__ __forceinline__ float wmax(float v){
  v = fmaxf(v, __shfl_xor(v, 32, 64)); v = fmaxf(v, __shfl_xor(v, 16, 64));
  v = fmaxf(v, __shfl_xor(v, 8, 64));  v = fmaxf(v, __shfl_xor(v, 4, 64));
  v = fmaxf(v, __shfl_xor(v, 2, 64));  v = fmaxf(v, __shfl_xor(v, 1, 64));
  return v;
}
__device__ __forceinline__ float breduce(float v, float* red){
  int tid = threadIdx.x;
  v = wsum(v);
  if ((tid & 63) == 0) red[tid >> 6] = v;
  __syncthreads();
  float r = red[0] + red[1] + red[2] + red[3];
  __syncthreads();
  return r;
}

// ---------------- device-coherent (cross-XCD) payload access ----------------
__device__ __forceinline__ float ldc(const float* p){
  return __hip_atomic_load(p, __ATOMIC_RELAXED, __HIP_MEMORY_SCOPE_AGENT);
}
__device__ __forceinline__ void stc(float* p, float v){
  __hip_atomic_store(p, v, __ATOMIC_RELAXED, __HIP_MEMORY_SCOPE_AGENT);
}

// ---- flat barrier, 128B-padded slots (one LLC line per block, no false sharing)
// payload ordering: vmcnt(0) drain + __syncthreads before slot store; payloads all
// go through stc/ldc (LLC-coherent), so relaxed slot ops suffice.
#define SLOT_STRIDE 32   // 32 u32 = 128 B
__device__ __forceinline__ void gsync(unsigned* slots, unsigned ep, int bid, int tid){
  asm volatile("s_waitcnt vmcnt(0)" ::: "memory");
  __syncthreads();
  if (tid == 0)
    __hip_atomic_store(&slots[bid * SLOT_STRIDE], ep, __ATOMIC_RELAXED, __HIP_MEMORY_SCOPE_AGENT);
  {
    unsigned spins = 0;
    while (__hip_atomic_load(&slots[tid * SLOT_STRIDE], __ATOMIC_RELAXED, __HIP_MEMORY_SCOPE_AGENT) < ep){
      if (++spins > 4194304u){
        unsigned s2 = 0;   // acquire fallback: livelock-proof, never taken normally
        while (__hip_atomic_load(&slots[tid * SLOT_STRIDE], __ATOMIC_ACQUIRE, __HIP_MEMORY_SCOPE_AGENT) < ep){
          __builtin_amdgcn_s_sleep(2);
          if (++s2 > 100000000u) break;
        }
        break;
      }
    }
  }
  __syncthreads();
  asm volatile("" ::: "memory");
}

// ---------------- precompute kernels ----------------
__global__ void pe_kernel(float* pe){
  int t = blockIdx.x;
  int pos = t % 30;
  for (int d = threadIdx.x; d < DIM; d += 256){
    int m = d >> 1;
    float div = __expf((float)(2 * m) * (-9.210340371976184f / 1024.0f));
    float arg = (float)pos * div;
    pe[t * DIM + d] = (d & 1) ? cosf(arg) : sinf(arg);
  }
}

__global__ void gemv_rows(const float* __restrict__ X, const float* __restrict__ W,
                          const float* __restrict__ b, float* __restrict__ Y,
                          int K, int R){
  int t = blockIdx.y;
  int r = blockIdx.x * 4 + (threadIdx.x >> 6);
  int lane = threadIdx.x & 63;
  const float* x  = X + (size_t)t * K;
  const float* wr = W + (size_t)r * K;
  float acc = 0.f;
  for (int d = lane; d < K; d += 64) acc = fmaf(wr[d], x[d], acc);
  acc = wsum(acc);
  if (lane == 0) Y[(size_t)t * R + r] = acc + b[r];
}

__global__ void matmul_nn_1024(const float* __restrict__ A, const float* __restrict__ B,
                               float* __restrict__ Cc){
  __shared__ float As[32][33];
  __shared__ float Bs[32][33];
  int tb = blockIdx.x * 32, ta = blockIdx.y * 32;
  int tx = threadIdx.x & 31, ty = threadIdx.x >> 5;
  float acc[4] = {0.f, 0.f, 0.f, 0.f};
  for (int k0 = 0; k0 < 1024; k0 += 32){
    for (int r = ty; r < 32; r += 8) As[r][tx] = A[(size_t)(ta + r) * 1024 + k0 + tx];
    for (int r = ty; r < 32; r += 8) Bs[r][tx] = B[(size_t)(k0 + r) * 1024 + tb + tx];
    __syncthreads();
    #pragma unroll
    for (int kk = 0; kk < 32; ++kk){
      float bv = Bs[kk][tx];
      #pragma unroll
      for (int m = 0; m < 4; ++m) acc[m] = fmaf(As[ty + 8 * m][kk], bv, acc[m]);
    }
    __syncthreads();
  }
  for (int m = 0; m < 4; ++m) Cc[(size_t)(ta + ty + 8 * m) * 1024 + tb + tx] = acc[m];
}

__global__ void cb_kernel(const float* __restrict__ vm_w, const float* __restrict__ vr_b,
                          const float* __restrict__ vm_b, const float* __restrict__ obj_w,
                          float* __restrict__ cb){
  int gw = blockIdx.x * 4 + (threadIdx.x >> 6);
  int lane = threadIdx.x & 63;
  const float* wr = vm_w + (size_t)gw * DIM;
  float acc = 0.f;
  for (int d = lane; d < DIM; d += 64) acc = fmaf(wr[d], vr_b[d], acc);
  acc = wsum(acc);
  if (lane == 0) cb[gw] = acc + vm_b[gw] + obj_w[(size_t)gw * 80];
}

// ---------------- the persistent autoregressive decode ----------------
struct CoopArgs {
  const float *sa_in_w, *sa_in_b, *sa_out_w, *sa_out_b;
  const float *ln1_g, *ln1_b, *ln2_g, *ln2_b, *ln3_g, *ln3_b;
  const float *ff1_w, *ff1_b, *ff2_w, *ff2_b;
  const float *vr_w, *vr_b, *obj_w;
  const float *pe, *cac, *Cm, *cb;
  float *emb, *kc, *vc, *q, *u, *hb, *w, *s;
  float *out;
  unsigned *bar;   // padded slots[256*SLOT_STRIDE]
};

__global__ void __launch_bounds__(256, 2) decode_loop(CoopArgs a){
  const int tid = threadIdx.x, bid = blockIdx.x;
  const int wave = tid >> 6, lane = tid & 63;
  const int gw = bid * 4 + wave;            // global wave id / output row, 0..1023
  __shared__ float sm[2048];
  __shared__ float scp[256];                // softmax probs [head][64]
  __shared__ float red[8];
  unsigned* slots = a.bar;
  unsigned ep = 0;

  // ---- preload this wave's hot weight rows (128 floats/thread)
  float wq[16], wk[16], wv[16], wo[16], f1a[16], f1b[16], f2[32];
  {
    const float* pq = a.sa_in_w + (size_t)gw * DIM;
    const float* pk = a.sa_in_w + (size_t)(DIM + gw) * DIM;
    const float* pv = a.sa_in_w + (size_t)(2 * DIM + gw) * DIM;
    const float* po = a.sa_out_w + (size_t)gw * DIM;
    const float* p1a = a.ff1_w + (size_t)(2 * gw) * DIM;
    const float* p1b = a.ff1_w + (size_t)(2 * gw + 1) * DIM;
    const float* p2 = a.ff2_w + (size_t)gw * 2048;
    #pragma unroll
    for (int k = 0; k < 16; ++k){
      int d = lane + 64 * k;
      wq[k] = pq[d]; wk[k] = pk[d]; wv[k] = pv[d]; wo[k] = po[d];
      f1a[k] = p1a[d]; f1b[k] = p1b[d];
    }
    #pragma unroll
    for (int k = 0; k < 32; ++k) f2[k] = p2[lane + 64 * k];
  }
  // per-row bias scalars
  const float b_q  = a.sa_in_b[gw];
  const float b_k  = a.sa_in_b[DIM + gw];
  const float b_v  = a.sa_in_b[2 * DIM + gw];
  const float b_o  = a.sa_out_b[gw];
  const float b_1a = a.ff1_b[2 * gw];
  const float b_1b = a.ff1_b[2 * gw + 1];
  const float b_2  = a.ff2_b[gw];
  const float b_vr = a.vr_b[gw];

  // running out-proj-projected V cache: lane j holds c^h_j = wo_gw[head h] . V_j[head h]
  float c0 = 0.f, c1 = 0.f, c2 = 0.f, c3 = 0.f;

  // score-block role: 16 blocks, head h = bid>>2, j-group jg = bid&3 (j = jg*16..+15)
  const bool is_score = (bid < 16);
  const int sc_h  = bid >> 2;
  const int sc_jg = bid & 3;
  const float sc_slope = 1.0f / (float)(4 << (2 * sc_h));   // 0.25^(h+1)

  // S0: emb row 0 = style
  if (bid == 0){
    for (int d = tid; d < DIM; d += 256) stc(a.emb + d, a.obj_w[(size_t)d * 80]);
  }
  ++ep; gsync(slots, ep, bid, tid);
  const float cbv = a.cb[gw];

  for (int i = 0; i < SEQ; ++i){
    const float* per = a.pe + i * DIM;

    // ---- S1: QKV gemv; q row, kc row i (row-major), vc row i
    {
      float* xs = sm;
      const float* er = a.emb + (size_t)i * DIM;
      for (int t = tid; t < DIM; t += 256) xs[t] = ldc(er + t) + per[t];
      __syncthreads();
      float aq = 0.f, ak = 0.f, av = 0.f;
      #pragma unroll
      for (int k = 0; k < 16; ++k){
        float x = xs[lane + 64 * k];
        aq = fmaf(wq[k], x, aq);
        ak = fmaf(wk[k], x, ak);
        av = fmaf(wv[k], x, av);
      }
      aq = wsum(aq); ak = wsum(ak); av = wsum(av);
      if (lane == 0){
        stc(a.q + gw, aq + b_q);
        stc(a.kc + (size_t)i * DIM + gw, ak + b_k);
        stc(a.vc + (size_t)i * DIM + gw, av + b_v);
      }
      __syncthreads();
    }
    ++ep; gsync(slots, ep, bid, tid);

    // ---- S2a: all blocks: c-update from V row i.  Score blocks: also s[h][j].
    {
      float* xs  = sm;          // V row i (1024)
      float* qsl = sm + 1024;   // q head-slice (256), score blocks only
      for (int t = tid; t < DIM; t += 256) xs[t] = ldc(a.vc + (size_t)i * DIM + t);
      if (is_score) qsl[tid] = ldc(a.q + sc_h * HDIM + tid);
      __syncthreads();
      float p0 = 0.f, p1 = 0.f, p2 = 0.f, p3 = 0.f;
      #pragma unroll
      for (int k = 0; k < 4; ++k){
        p0 = fmaf(wo[k],      xs[lane + 64 * k],        p0);
        p1 = fmaf(wo[k + 4],  xs[lane + 64 * (k + 4)],  p1);
        p2 = fmaf(wo[k + 8],  xs[lane + 64 * (k + 8)],  p2);
        p3 = fmaf(wo[k + 12], xs[lane + 64 * (k + 12)], p3);
      }
      p0 = wsum(p0); p1 = wsum(p1); p2 = wsum(p2); p3 = wsum(p3);
      if (lane == i){ c0 = p0; c1 = p1; c2 = p2; c3 = p3; }
      if (is_score){
        #pragma unroll
        for (int jj = 0; jj < 4; ++jj){
          int j = sc_jg * 16 + wave * 4 + jj;
          if (j <= i){
            const float* kr = a.kc + (size_t)j * DIM + sc_h * HDIM;
            float acc = 0.f;
            #pragma unroll
            for (int m = 0; m < 4; ++m)
              acc = fmaf(qsl[m * 64 + lane], ldc(kr + m * 64 + lane), acc);
            acc = wsum(acc);
            if (lane == 0)
              stc(a.s + sc_h * 64 + j, acc * 0.0625f - sc_slope * (float)((i - j) / 30));
          }
        }
      }
      __syncthreads();
    }
    ++ep; gsync(slots, ep, bid, tid);

    // ---- S2b: softmax (wave = head) + u_gw = sum_h sum_j p^h_j c^h_j + residual
    {
      const int h = wave;
      float sv = (lane <= i) ? ldc(a.s + h * 64 + lane) : -3.0e38f;
      float mx = wmax(sv);
      float p = (lane <= i) ? __expf(sv - mx) : 0.f;
      float sum = wsum(p);
      scp[h * 64 + lane] = p / sum;
      __syncthreads();
      float t = scp[lane] * c0 + scp[64 + lane] * c1 + scp[128 + lane] * c2 + scp[192 + lane] * c3;
      t = wsum(t);
      if (lane == 0){
        float x = ldc(a.emb + (size_t)i * DIM + gw) + per[gw];
        stc(a.u + gw, x + t + b_o);
      }
      __syncthreads();
    }
    ++ep; gsync(slots, ep, bid, tid);

    // ---- S3: ln1 -> +ca_contrib -> ln2 (local) ; ff1 rows -> hb
    float x2v;
    {
      float* xs = sm;
      for (int t = tid; t < DIM; t += 256) xs[t] = ldc(a.u + t);
      __syncthreads();
      float s0 = 0.f;
      #pragma unroll
      for (int k = 0; k < 4; ++k) s0 += xs[tid + 256 * k];
      float mean = breduce(s0, red) * (1.f / 1024.f);
      float s1 = 0.f;
      #pragma unroll
      for (int k = 0; k < 4; ++k){ float dd = xs[tid + 256 * k] - mean; s1 = fmaf(dd, dd, s1); }
      float var = breduce(s1, red) * (1.f / 1024.f);
      float rs = 1.f / sqrtf(var + 1e-5f);
      float tv[4];
      #pragma unroll
      for (int k = 0; k < 4; ++k){
        int d = tid + 256 * k;
        float x1 = (xs[d] - mean) * rs * a.ln1_g[d] + a.ln1_b[d];
        tv[k] = x1 + a.cac[(size_t)i * DIM + d];
      }
      float t0 = tv[0] + tv[1] + tv[2] + tv[3];
      float mean2 = breduce(t0, red) * (1.f / 1024.f);
      float t1 = 0.f;
      #pragma unroll
      for (int k = 0; k < 4; ++k){ float dd = tv[k] - mean2; t1 = fmaf(dd, dd, t1); }
      float var2 = breduce(t1, red) * (1.f / 1024.f);
      float rs2 = 1.f / sqrtf(var2 + 1e-5f);
      #pragma unroll
      for (int k = 0; k < 4; ++k){
        int d = tid + 256 * k;
        xs[d] = (tv[k] - mean2) * rs2 * a.ln2_g[d] + a.ln2_b[d];
      }
      __syncthreads();
      x2v = xs[gw];
      float acc0 = 0.f, acc1 = 0.f;
      #pragma unroll
      for (int k = 0; k < 16; ++k){
        float x = xs[lane + 64 * k];
        acc0 = fmaf(f1a[k], x, acc0);
        acc1 = fmaf(f1b[k], x, acc1);
      }
      acc0 = wsum(acc0); acc1 = wsum(acc1);
      if (lane == 0){
        stc(a.hb + 2 * gw,     fmaxf(acc0 + b_1a, 0.f));
        stc(a.hb + 2 * gw + 1, fmaxf(acc1 + b_1b, 0.f));
      }
      __syncthreads();
    }
    ++ep; gsync(slots, ep, bid, tid);

    // ---- S4: w = x2 + h @ ff2_w.T + b ; prefetch S5's vr_w/Cm rows
    float vrr[16], cmr[16];
    {
      float* hsm = sm;
      for (int t = tid; t < 2048; t += 256) hsm[t] = ldc(a.hb + t);
      const float* pr = a.vr_w + (size_t)gw * DIM;
      const float* pc = a.Cm + (size_t)gw * DIM;
      #pragma unroll
      for (int k = 0; k < 16; ++k){ vrr[k] = pr[lane + 64 * k]; cmr[k] = pc[lane + 64 * k]; }
      __syncthreads();
      float acc = 0.f;
      #pragma unroll
      for (int k = 0; k < 32; ++k) acc = fmaf(f2[k], hsm[lane + 64 * k], acc);
      acc = wsum(acc);
      if (lane == 0) stc(a.w + gw, x2v + acc + b_2);
      __syncthreads();
    }
    ++ep; gsync(slots, ep, bid, tid);

    // ---- S5: ln3; final-output row i; recurrence new_tok -> emb[i+1]
    {
      float* xs = sm;
      for (int t = tid; t < DIM; t += 256) xs[t] = ldc(a.w + t);
      __syncthreads();
      float s0 = 0.f;
      #pragma unroll
      for (int k = 0; k < 4; ++k) s0 += xs[tid + 256 * k];
      float mean = breduce(s0, red) * (1.f / 1024.f);
      float s1 = 0.f;
      #pragma unroll
      for (int k = 0; k < 4; ++k){ float dd = xs[tid + 256 * k] - mean; s1 = fmaf(dd, dd, s1); }
      float var = breduce(s1, red) * (1.f / 1024.f);
      float rs = 1.f / sqrtf(var + 1e-5f);
      float ov[4];
      #pragma unroll
      for (int k = 0; k < 4; ++k){
        int d = tid + 256 * k;
        ov[k] = (xs[d] - mean) * rs * a.ln3_g[d] + a.ln3_b[d];
      }
      __syncthreads();
      #pragma unroll
      for (int k = 0; k < 4; ++k) xs[tid + 256 * k] = ov[k];
      __syncthreads();
      {
        float ar = 0.f, ac = 0.f;
        #pragma unroll
        for (int k = 0; k < 16; ++k){
          float x = xs[lane + 64 * k];
          ar = fmaf(vrr[k], x, ar);
          ac = fmaf(cmr[k], x, ac);
        }
        ar = wsum(ar); ac = wsum(ac);
        if (lane == 0){
          a.out[(size_t)i * DIM + gw] = ar + b_vr;
          if (i < SEQ - 1) stc(a.emb + (size_t)(i + 1) * DIM + gw, ac + cbv);
        }
      }
      __syncthreads();
    }
    ++ep; gsync(slots, ep, bid, tid);
  }
}

// ---------------- host launcher ----------------
extern "C" void kernel_launch(void* const* d_in, const int* in_sizes, int n_in,
                              void* d_out, int out_size, void* d_ws, size_t ws_size,
                              hipStream_t stream){
  const float* hs       = (const float*)d_in[0];
  const float* hid_w    = (const float*)d_in[1];
  const float* hid_b    = (const float*)d_in[2];
  const float* obj_w    = (const float*)d_in[3];
  const float* sa_in_w  = (const float*)d_in[4];
  const float* sa_in_b  = (const float*)d_in[5];
  const float* sa_out_w = (const float*)d_in[6];
  const float* sa_out_b = (const float*)d_in[7];
  const float* ca_in_w  = (const float*)d_in[8];
  const float* ca_in_b  = (const float*)d_in[9];
  const float* ca_out_w = (const float*)d_in[10];
  const float* ca_out_b = (const float*)d_in[11];
  const float* ln1_g    = (const float*)d_in[12];
  const float* ln1_b    = (const float*)d_in[13];
  const float* ln2_g    = (const float*)d_in[14];
  const float* ln2_b    = (const float*)d_in[15];
  const float* ln3_g    = (const float*)d_in[16];
  const float* ln3_b    = (const float*)d_in[17];
  const float* ff1_w    = (const float*)d_in[18];
  const float* ff1_b    = (const float*)d_in[19];
  const float* ff2_w    = (const float*)d_in[20];
  const float* ff2_b    = (const float*)d_in[21];
  const float* vr_w     = (const float*)d_in[22];
  const float* vr_b     = (const float*)d_in[23];
  const float* vm_w     = (const float*)d_in[24];
  const float* vm_b     = (const float*)d_in[25];

  float* ws = (float*)d_ws;
  float* pe   = ws;                 // 65536
  float* emb  = ws + 65536;         // 65536
  float* kc   = ws + 131072;        // 65536 (row-major [i][dim])
  float* vc   = ws + 196608;        // 65536 (row-major [i][dim])
  float* mem  = ws + 262144;        // 65536
  float* vtmp = ws + 327680;        // 65536
  float* cac  = ws + 393216;        // 65536
  float* Cm   = ws + 458752;        // 1048576
  float* q    = ws + 1507328;       // 1024
  float* u    = ws + 1508352;       // 1024
  float* hb   = ws + 1509376;       // 2048
  float* wv   = ws + 1511424;       // 1024
  float* cb   = ws + 1512448;       // 1024
  float* sbuf = ws + 1513472;       // 1024 (scores s[h][64], 256 used)
  unsigned* bar = (unsigned*)(ws + 1514496);  // padded slots: 256 * 128B = 32KB

  hipMemsetAsync((void*)bar, 0, 256 * SLOT_STRIDE * 4, stream);

  pe_kernel<<<SEQ, 256, 0, stream>>>(pe);
  gemv_rows<<<dim3(256, SEQ), 256, 0, stream>>>(hs, hid_w, hid_b, mem, 1024, 1024);
  gemv_rows<<<dim3(256, SEQ), 256, 0, stream>>>(mem, ca_in_w + 2048 * 1024, ca_in_b + 2048, vtmp, 1024, 1024);
  gemv_rows<<<dim3(256, SEQ), 256, 0, stream>>>(vtmp, ca_out_w, ca_out_b, cac, 1024, 1024);
  matmul_nn_1024<<<dim3(32, 32), 256, 0, stream>>>(vm_w, vr_w, Cm);
  cb_kernel<<<256, 256, 0, stream>>>(vm_w, vr_b, vm_b, obj_w, cb);

  CoopArgs A;
  A.sa_in_w = sa_in_w; A.sa_in_b = sa_in_b; A.sa_out_w = sa_out_w; A.sa_out_b = sa_out_b;
  A.ln1_g = ln1_g; A.ln1_b = ln1_b; A.ln2_g = ln2_g; A.ln2_b = ln2_b; A.ln3_g = ln3_g; A.ln3_b = ln3_b;
  A.ff1_w = ff1_w; A.ff1_b = ff1_b; A.ff2_w = ff2_w; A.ff2_b = ff2_b;
  A.vr_w = vr_w; A.vr_b = vr_b; A.obj_w = obj_w;
  A.pe = pe; A.cac = cac; A.Cm = Cm; A.cb = cb;
  A.emb = emb; A.kc = kc; A.vc = vc; A.q = q; A.u = u; A.hb = hb; A.w = wv; A.s = sbuf;
  A.out = (float*)d_out;
  A.bar = bar;

  void* params[1] = { &A };
  hipError_t e = hipLaunchCooperativeKernel((void*)decode_loop, dim3(NBLK), dim3(256), params, 0, stream);
  if (e != hipSuccess){
    decode_loop<<<dim3(NBLK), dim3(256), 0, stream>>>(A);
  }
}

// Round 8
// 2175.892 us; speedup vs baseline: 1.6121x; 1.0701x over previous
//
#include <hip/hip_runtime.h>
#include <math.h>

#define DIM  1024
#define SEQ  64
#define HDIM 256
#define NBLK 256

// ---------------- wave / block reduction helpers ----------------
__device__ __forceinline__ float wsum(float v){
  v += __shfl_xor(v, 32, 64); v += __shfl_xor(v, 16, 64); v += __shfl_xor(v, 8, 64);
  v += __shfl_xor(v, 4, 64);  v += __shfl_xor(v, 2, 64);  v += __shfl_xor(v, 1, 64);
  return v;
}
__device__ __forceinline__ float wmax(float v){
  v = fmaxf(v, __shfl_xor(v, 32, 64)); v = fmaxf(v, __shfl_xor(v, 16, 64));
  v = fmaxf(v, __shfl_xor(v, 8, 64));  v = fmaxf(v, __shfl_xor(v, 4, 64));
  v = fmaxf(v, __shfl_xor(v, 2, 64));  v = fmaxf(v, __shfl_xor(v, 1, 64));
  return v;
}
// fused 2-value block reduce: one LDS round + one __syncthreads pair
__device__ __forceinline__ float2 breduce2(float va, float vb, float* red){
  int tid = threadIdx.x;
  va = wsum(va); vb = wsum(vb);
  if ((tid & 63) == 0){ red[(tid >> 6) * 2] = va; red[(tid >> 6) * 2 + 1] = vb; }
  __syncthreads();
  float ra = red[0] + red[2] + red[4] + red[6];
  float rb = red[1] + red[3] + red[5] + red[7];
  __syncthreads();
  return make_float2(ra, rb);
}

// ---------------- device-coherent (cross-XCD) payload access ----------------
__device__ __forceinline__ float ldc(const float* p){
  return __hip_atomic_load(p, __ATOMIC_RELAXED, __HIP_MEMORY_SCOPE_AGENT);
}
__device__ __forceinline__ void stc(float* p, float v){
  __hip_atomic_store(p, v, __ATOMIC_RELAXED, __HIP_MEMORY_SCOPE_AGENT);
}

__device__ __forceinline__ void spin_ge(unsigned* p, unsigned ep){
  unsigned spins = 0;
  while (__hip_atomic_load(p, __ATOMIC_RELAXED, __HIP_MEMORY_SCOPE_AGENT) < ep){
    if (++spins > 4194304u){
      unsigned s2 = 0;   // acquire fallback: livelock-proof, never taken normally
      while (__hip_atomic_load(p, __ATOMIC_ACQUIRE, __HIP_MEMORY_SCOPE_AGENT) < ep){
        __builtin_amdgcn_s_sleep(2);
        if (++s2 > 100000000u) break;
      }
      return;
    }
  }
}

// ---- flat barrier, 128B-padded slots ----
#define SLOT_STRIDE 32   // 32 u32 = 128 B
__device__ __forceinline__ void gsync(unsigned* slots, unsigned ep, int bid, int tid){
  asm volatile("s_waitcnt vmcnt(0)" ::: "memory");
  __syncthreads();
  if (tid == 0)
    __hip_atomic_store(&slots[bid * SLOT_STRIDE], ep, __ATOMIC_RELAXED, __HIP_MEMORY_SCOPE_AGENT);
  spin_ge(&slots[tid * SLOT_STRIDE], ep);
  __syncthreads();
  asm volatile("" ::: "memory");
}

// ---------------- Cm = vm_w @ vr_w (only remaining prologue kernel) ----------------
__global__ void matmul_nn_1024(const float* __restrict__ A, const float* __restrict__ B,
                               float* __restrict__ Cc){
  __shared__ float As[32][33];
  __shared__ float Bs[32][33];
  int tb = blockIdx.x * 32, ta = blockIdx.y * 32;
  int tx = threadIdx.x & 31, ty = threadIdx.x >> 5;
  float acc[4] = {0.f, 0.f, 0.f, 0.f};
  for (int k0 = 0; k0 < 1024; k0 += 32){
    for (int r = ty; r < 32; r += 8) As[r][tx] = A[(size_t)(ta + r) * 1024 + k0 + tx];
    for (int r = ty; r < 32; r += 8) Bs[r][tx] = B[(size_t)(k0 + r) * 1024 + tb + tx];
    __syncthreads();
    #pragma unroll
    for (int kk = 0; kk < 32; ++kk){
      float bv = Bs[kk][tx];
      #pragma unroll
      for (int m = 0; m < 4; ++m) acc[m] = fmaf(As[ty + 8 * m][kk], bv, acc[m]);
    }
    __syncthreads();
  }
  for (int m = 0; m < 4; ++m) Cc[(size_t)(ta + ty + 8 * m) * 1024 + tb + tx] = acc[m];
}

// ---------------- the persistent autoregressive decode ----------------
struct CoopArgs {
  const float *hs, *hid_w, *hid_b;
  const float *sa_in_w, *sa_in_b, *sa_out_w, *sa_out_b;
  const float *ca_in_w, *ca_in_b, *ca_out_w, *ca_out_b;
  const float *ln1_g, *ln1_b, *ln2_g, *ln2_b, *ln3_g, *ln3_b;
  const float *ff1_w, *ff1_b, *ff2_w, *ff2_b;
  const float *vr_w, *vr_b, *vm_w, *vm_b, *obj_w;
  const float *Cm;
  float *pe, *emb, *kc, *vc, *mem, *vtmp, *cac, *q, *u, *hb, *w, *s;
  float *out;
  unsigned *bar;     // padded slots[256*SLOT_STRIDE]
  unsigned *flags;   // 16 padded score flags
};

__global__ void __launch_bounds__(256, 2) decode_loop(CoopArgs a){
  const int tid = threadIdx.x, bid = blockIdx.x;
  const int wave = tid >> 6, lane = tid & 63;
  const int gw = bid * 4 + wave;            // global wave id / output row, 0..1023
  __shared__ float sm[2048];
  __shared__ float scp[256];
  __shared__ float red[8];
  unsigned* slots = a.bar;
  unsigned ep = 0;

  // pe constants for this wave's column gw
  const float NLOG = -9.210340371976184f / 1024.0f;   // -ln(10000)/D
  const float divw = __expf((float)(2 * (gw >> 1)) * NLOG);
  const int parw = gw & 1;

  // ======== P-stages: prologue folded into the kernel (each wave: ALL 64 t) ========
  // P1: mem[t][gw] = hid_w[gw].hs[t] + hid_b[gw]; pe table; emb row 0
  {
    float pw[16];
    const float* pr = a.hid_w + (size_t)gw * DIM;
    #pragma unroll
    for (int k = 0; k < 16; ++k) pw[k] = pr[lane + 64 * k];
    float bias = a.hid_b[gw];
    for (int t = 0; t < 64; ++t){
      const float* xr = a.hs + (size_t)t * DIM;
      float acc = 0.f;
      #pragma unroll
      for (int k = 0; k < 16; ++k) acc = fmaf(pw[k], xr[lane + 64 * k], acc);
      acc = wsum(acc);
      if (lane == 0) stc(a.mem + (size_t)t * DIM + gw, acc + bias);
    }
    // pe[t][gw], t = lane (precise sinf/cosf, computed once)
    {
      float arg = (float)(lane % 30) * divw;
      float pev = parw ? cosf(arg) : sinf(arg);
      stc(a.pe + (size_t)lane * DIM + gw, pev);
    }
    if (bid == 0){
      for (int d = tid; d < DIM; d += 256) stc(a.emb + d, a.obj_w[(size_t)d * 80]);
    }
  }
  ++ep; gsync(slots, ep, bid, tid);

  // P2: vtmp[t][gw] = ca_wv[gw].mem[t] + ca_bv[gw]  (row staged in LDS per block)
  {
    float pw[16];
    const float* pr = a.ca_in_w + (size_t)(2 * DIM + gw) * DIM;
    #pragma unroll
    for (int k = 0; k < 16; ++k) pw[k] = pr[lane + 64 * k];
    float bias = a.ca_in_b[2 * DIM + gw];
    for (int t = 0; t < 64; ++t){
      const float* xr = a.mem + (size_t)t * DIM;
      #pragma unroll
      for (int k = 0; k < 4; ++k) sm[tid + 256 * k] = ldc(xr + tid + 256 * k);
      __syncthreads();
      float acc = 0.f;
      #pragma unroll
      for (int k = 0; k < 16; ++k) acc = fmaf(pw[k], sm[lane + 64 * k], acc);
      acc = wsum(acc);
      if (lane == 0) stc(a.vtmp + (size_t)t * DIM + gw, acc + bias);
      __syncthreads();
    }
  }
  ++ep; gsync(slots, ep, bid, tid);

  // P3: cac[t][gw] = ca_out_w[gw].vtmp[t] + ca_out_b[gw]
  {
    float pw[16];
    const float* pr = a.ca_out_w + (size_t)gw * DIM;
    #pragma unroll
    for (int k = 0; k < 16; ++k) pw[k] = pr[lane + 64 * k];
    float bias = a.ca_out_b[gw];
    for (int t = 0; t < 64; ++t){
      const float* xr = a.vtmp + (size_t)t * DIM;
      #pragma unroll
      for (int k = 0; k < 4; ++k) sm[tid + 256 * k] = ldc(xr + tid + 256 * k);
      __syncthreads();
      float acc = 0.f;
      #pragma unroll
      for (int k = 0; k < 16; ++k) acc = fmaf(pw[k], sm[lane + 64 * k], acc);
      acc = wsum(acc);
      if (lane == 0) stc(a.cac + (size_t)t * DIM + gw, acc + bias);
      __syncthreads();
    }
  }
  ++ep; gsync(slots, ep, bid, tid);

  // ---- main weight rows into registers (128 floats/thread)
  float wq[16], wk[16], wv[16], wo[16], f1a[16], f1b[16], f2[32];
  {
    const float* pq = a.sa_in_w + (size_t)gw * DIM;
    const float* pk = a.sa_in_w + (size_t)(DIM + gw) * DIM;
    const float* pv = a.sa_in_w + (size_t)(2 * DIM + gw) * DIM;
    const float* po = a.sa_out_w + (size_t)gw * DIM;
    const float* p1a = a.ff1_w + (size_t)(2 * gw) * DIM;
    const float* p1b = a.ff1_w + (size_t)(2 * gw + 1) * DIM;
    const float* p2 = a.ff2_w + (size_t)gw * 2048;
    #pragma unroll
    for (int k = 0; k < 16; ++k){
      int d = lane + 64 * k;
      wq[k] = pq[d]; wk[k] = pk[d]; wv[k] = pv[d]; wo[k] = po[d];
      f1a[k] = p1a[d]; f1b[k] = p1b[d];
    }
    #pragma unroll
    for (int k = 0; k < 32; ++k) f2[k] = p2[lane + 64 * k];
  }
  // per-row bias scalars
  const float b_q  = a.sa_in_b[gw];
  const float b_k  = a.sa_in_b[DIM + gw];
  const float b_v  = a.sa_in_b[2 * DIM + gw];
  const float b_o  = a.sa_out_b[gw];
  const float b_1a = a.ff1_b[2 * gw];
  const float b_1b = a.ff1_b[2 * gw + 1];
  const float b_2  = a.ff2_b[gw];
  const float b_vr = a.vr_b[gw];
  // cb[gw] = vm_w[gw] . vr_b + vm_b[gw] + style[gw]
  float cbv;
  {
    const float* pv = a.vm_w + (size_t)gw * DIM;
    float acc = 0.f;
    #pragma unroll
    for (int k = 0; k < 16; ++k) acc = fmaf(pv[lane + 64 * k], a.vr_b[lane + 64 * k], acc);
    cbv = wsum(acc) + a.vm_b[gw] + a.obj_w[(size_t)gw * 80];
  }

  // running projected-V cache: lane j holds c^h_j = wo_gw[head h] . V_j[head h]
  float c0 = 0.f, c1 = 0.f, c2 = 0.f, c3 = 0.f;

  const bool is_score = (bid < 16);
  const int sc_h  = bid >> 2;
  const int sc_jg = bid & 3;
  const float sc_slope = 1.0f / (float)(4 << (2 * sc_h));   // 0.25^(h+1)

  for (int i = 0; i < SEQ; ++i){
    const float* per = a.pe + (size_t)i * DIM;

    // ---- S1: QKV gemv; q row, kc row i, vc row i
    {
      float* xs = sm;
      const float* er = a.emb + (size_t)i * DIM;
      #pragma unroll
      for (int k = 0; k < 4; ++k){
        int d = tid + 256 * k;
        xs[d] = ldc(er + d) + ldc(per + d);
      }
      __syncthreads();
      float aq = 0.f, ak = 0.f, av = 0.f;
      #pragma unroll
      for (int k = 0; k < 16; ++k){
        float x = xs[lane + 64 * k];
        aq = fmaf(wq[k], x, aq);
        ak = fmaf(wk[k], x, ak);
        av = fmaf(wv[k], x, av);
      }
      aq = wsum(aq); ak = wsum(ak); av = wsum(av);
      if (lane == 0){
        stc(a.q + gw, aq + b_q);
        stc(a.kc + (size_t)i * DIM + gw, ak + b_k);
        stc(a.vc + (size_t)i * DIM + gw, av + b_v);
      }
      __syncthreads();
    }
    ++ep; gsync(slots, ep, bid, tid);

    // ---- S2: c-update (all) || scores (16 blocks) -> flag -> softmax -> u
    {
      float* xs  = sm;          // V row i
      float* qsl = sm + 1024;   // q head-slice (score blocks)
      float remb = ldc(a.emb + (size_t)i * DIM + gw);   // residual, issued early
      #pragma unroll
      for (int k = 0; k < 4; ++k) xs[tid + 256 * k] = ldc(a.vc + (size_t)i * DIM + tid + 256 * k);
      if (is_score) qsl[tid] = ldc(a.q + sc_h * HDIM + tid);
      __syncthreads();
      // c-update
      float p0 = 0.f, p1 = 0.f, p2 = 0.f, p3 = 0.f;
      #pragma unroll
      for (int k = 0; k < 4; ++k){
        p0 = fmaf(wo[k],      xs[lane + 64 * k],        p0);
        p1 = fmaf(wo[k + 4],  xs[lane + 64 * (k + 4)],  p1);
        p2 = fmaf(wo[k + 8],  xs[lane + 64 * (k + 8)],  p2);
        p3 = fmaf(wo[k + 12], xs[lane + 64 * (k + 12)], p3);
      }
      p0 = wsum(p0); p1 = wsum(p1); p2 = wsum(p2); p3 = wsum(p3);
      if (lane == i){ c0 = p0; c1 = p1; c2 = p2; c3 = p3; }
      // scores + flag (score blocks only; block-uniform branch)
      if (is_score){
        #pragma unroll
        for (int jj = 0; jj < 4; ++jj){
          int j = sc_jg * 16 + wave * 4 + jj;
          if (j <= i){
            const float* kr = a.kc + (size_t)j * DIM + sc_h * HDIM;
            float acc = 0.f;
            #pragma unroll
            for (int m = 0; m < 4; ++m)
              acc = fmaf(qsl[m * 64 + lane], ldc(kr + m * 64 + lane), acc);
            acc = wsum(acc);
            if (lane == 0)
              stc(a.s + sc_h * 64 + j, acc * 0.0625f - sc_slope * (float)((i - j) / 30));
          }
        }
        asm volatile("s_waitcnt vmcnt(0)" ::: "memory");
        __syncthreads();
        if (tid == 0)
          __hip_atomic_store(&a.flags[bid * SLOT_STRIDE], (unsigned)(i + 1),
                             __ATOMIC_RELAXED, __HIP_MEMORY_SCOPE_AGENT);
      }
      // all blocks: wait for the 16 score flags
      if (tid < 16) spin_ge(&a.flags[tid * SLOT_STRIDE], (unsigned)(i + 1));
      __syncthreads();
      // softmax (wave = head)
      {
        const int h = wave;
        float sv = (lane <= i) ? ldc(a.s + h * 64 + lane) : -3.0e38f;
        float mx = wmax(sv);
        float p = (lane <= i) ? __expf(sv - mx) : 0.f;
        float sum = wsum(p);
        scp[h * 64 + lane] = p / sum;
      }
      __syncthreads();
      // u_gw = sum_h sum_j p^h_j c^h_j + residual
      float t = scp[lane] * c0 + scp[64 + lane] * c1 + scp[128 + lane] * c2 + scp[192 + lane] * c3;
      t = wsum(t);
      if (lane == 0){
        stc(a.u + gw, remb + ldc(per + gw) + t + b_o);
      }
      __syncthreads();
    }
    ++ep; gsync(slots, ep, bid, tid);

    // ---- S3: ln1 -> +ca_contrib -> ln2 (single-pass stats) ; ff1 -> hb
    float x2v;
    {
      float* xs = sm;
      #pragma unroll
      for (int k = 0; k < 4; ++k) xs[tid + 256 * k] = ldc(a.u + tid + 256 * k);
      __syncthreads();
      float sa = 0.f, sb = 0.f;
      #pragma unroll
      for (int k = 0; k < 4; ++k){ float x = xs[tid + 256 * k]; sa += x; sb = fmaf(x, x, sb); }
      float2 r = breduce2(sa, sb, red);
      float mean = r.x * (1.f / 1024.f);
      float var = r.y * (1.f / 1024.f) - mean * mean;
      float rs = 1.f / sqrtf(var + 1e-5f);
      float tv[4];
      float ta = 0.f, tb = 0.f;
      #pragma unroll
      for (int k = 0; k < 4; ++k){
        int d = tid + 256 * k;
        float x1 = (xs[d] - mean) * rs * a.ln1_g[d] + a.ln1_b[d];
        tv[k] = x1 + ldc(a.cac + (size_t)i * DIM + d);
        ta += tv[k]; tb = fmaf(tv[k], tv[k], tb);
      }
      float2 r2 = breduce2(ta, tb, red);
      float mean2 = r2.x * (1.f / 1024.f);
      float var2 = r2.y * (1.f / 1024.f) - mean2 * mean2;
      float rs2 = 1.f / sqrtf(var2 + 1e-5f);
      #pragma unroll
      for (int k = 0; k < 4; ++k){
        int d = tid + 256 * k;
        xs[d] = (tv[k] - mean2) * rs2 * a.ln2_g[d] + a.ln2_b[d];
      }
      __syncthreads();
      x2v = xs[gw];
      float acc0 = 0.f, acc1 = 0.f;
      #pragma unroll
      for (int k = 0; k < 16; ++k){
        float x = xs[lane + 64 * k];
        acc0 = fmaf(f1a[k], x, acc0);
        acc1 = fmaf(f1b[k], x, acc1);
      }
      acc0 = wsum(acc0); acc1 = wsum(acc1);
      if (lane == 0){
        stc(a.hb + 2 * gw,     fmaxf(acc0 + b_1a, 0.f));
        stc(a.hb + 2 * gw + 1, fmaxf(acc1 + b_1b, 0.f));
      }
      __syncthreads();
    }
    ++ep; gsync(slots, ep, bid, tid);

    // ---- S4: w = x2 + h @ ff2_w.T + b ; prefetch S5's vr_w/Cm rows
    float vrr[16], cmr[16];
    {
      float* hsm = sm;
      #pragma unroll
      for (int k = 0; k < 8; ++k) hsm[tid + 256 * k] = ldc(a.hb + tid + 256 * k);
      const float* pr = a.vr_w + (size_t)gw * DIM;
      const float* pc = a.Cm + (size_t)gw * DIM;
      #pragma unroll
      for (int k = 0; k < 16; ++k){ vrr[k] = pr[lane + 64 * k]; cmr[k] = pc[lane + 64 * k]; }
      __syncthreads();
      float acc = 0.f;
      #pragma unroll
      for (int k = 0; k < 32; ++k) acc = fmaf(f2[k], hsm[lane + 64 * k], acc);
      acc = wsum(acc);
      if (lane == 0) stc(a.w + gw, x2v + acc + b_2);
      __syncthreads();
    }
    ++ep; gsync(slots, ep, bid, tid);

    // ---- S5: ln3 (single-pass); out row i; recurrence -> emb[i+1]
    {
      float* xs = sm;
      #pragma unroll
      for (int k = 0; k < 4; ++k) xs[tid + 256 * k] = ldc(a.w + tid + 256 * k);
      __syncthreads();
      float sa = 0.f, sb = 0.f;
      #pragma unroll
      for (int k = 0; k < 4; ++k){ float x = xs[tid + 256 * k]; sa += x; sb = fmaf(x, x, sb); }
      float2 r = breduce2(sa, sb, red);
      float mean = r.x * (1.f / 1024.f);
      float var = r.y * (1.f / 1024.f) - mean * mean;
      float rs = 1.f / sqrtf(var + 1e-5f);
      float ov[4];
      #pragma unroll
      for (int k = 0; k < 4; ++k){
        int d = tid + 256 * k;
        ov[k] = (xs[d] - mean) * rs * a.ln3_g[d] + a.ln3_b[d];
      }
      __syncthreads();
      #pragma unroll
      for (int k = 0; k < 4; ++k) xs[tid + 256 * k] = ov[k];
      __syncthreads();
      {
        float ar = 0.f, ac = 0.f;
        #pragma unroll
        for (int k = 0; k < 16; ++k){
          float x = xs[lane + 64 * k];
          ar = fmaf(vrr[k], x, ar);
          ac = fmaf(cmr[k], x, ac);
        }
        ar = wsum(ar); ac = wsum(ac);
        if (lane == 0){
          a.out[(size_t)i * DIM + gw] = ar + b_vr;
          if (i < SEQ - 1) stc(a.emb + (size_t)(i + 1) * DIM + gw, ac + cbv);
        }
      }
      __syncthreads();
    }
    ++ep; gsync(slots, ep, bid, tid);
  }
}

// ---------------- host launcher ----------------
extern "C" void kernel_launch(void* const* d_in, const int* in_sizes, int n_in,
                              void* d_out, int out_size, void* d_ws, size_t ws_size,
                              hipStream_t stream){
  const float* hs       = (const float*)d_in[0];
  const float* hid_w    = (const float*)d_in[1];
  const float* hid_b    = (const float*)d_in[2];
  const float* obj_w    = (const float*)d_in[3];
  const float* sa_in_w  = (const float*)d_in[4];
  const float* sa_in_b  = (const float*)d_in[5];
  const float* sa_out_w = (const float*)d_in[6];
  const float* sa_out_b = (const float*)d_in[7];
  const float* ca_in_w  = (const float*)d_in[8];
  const float* ca_in_b  = (const float*)d_in[9];
  const float* ca_out_w = (const float*)d_in[10];
  const float* ca_out_b = (const float*)d_in[11];
  const float* ln1_g    = (const float*)d_in[12];
  const float* ln1_b    = (const float*)d_in[13];
  const float* ln2_g    = (const float*)d_in[14];
  const float* ln2_b    = (const float*)d_in[15];
  const float* ln3_g    = (const float*)d_in[16];
  const float* ln3_b    = (const float*)d_in[17];
  const float* ff1_w    = (const float*)d_in[18];
  const float* ff1_b    = (const float*)d_in[19];
  const float* ff2_w    = (const float*)d_in[20];
  const float* ff2_b    = (const float*)d_in[21];
  const float* vr_w     = (const float*)d_in[22];
  const float* vr_b     = (const float*)d_in[23];
  const float* vm_w     = (const float*)d_in[24];
  const float* vm_b     = (const float*)d_in[25];

  float* ws = (float*)d_ws;
  float* pe   = ws;                 // 65536
  float* emb  = ws + 65536;         // 65536
  float* kc   = ws + 131072;        // 65536
  float* vc   = ws + 196608;        // 65536
  float* mem  = ws + 262144;        // 65536
  float* vtmp = ws + 327680;        // 65536
  float* cac  = ws + 393216;        // 65536
  float* Cm   = ws + 458752;        // 1048576
  float* q    = ws + 1507328;       // 1024
  float* u    = ws + 1508352;       // 1024
  float* hb   = ws + 1509376;       // 2048
  float* wv   = ws + 1511424;       // 1024
  float* sbuf = ws + 1512448;       // 1024
  unsigned* bar   = (unsigned*)(ws + 1513472);   // 256*128B = 32KB
  unsigned* flags = bar + 256 * SLOT_STRIDE;     // 16*128B = 2KB

  hipMemsetAsync((void*)bar, 0, (256 + 16) * SLOT_STRIDE * 4, stream);

  // Cm = vm_w @ vr_w  (folds the two recurrence gemvs)
  matmul_nn_1024<<<dim3(32, 32), 256, 0, stream>>>(vm_w, vr_w, Cm);

  CoopArgs A;
  A.hs = hs; A.hid_w = hid_w; A.hid_b = hid_b;
  A.sa_in_w = sa_in_w; A.sa_in_b = sa_in_b; A.sa_out_w = sa_out_w; A.sa_out_b = sa_out_b;
  A.ca_in_w = ca_in_w; A.ca_in_b = ca_in_b; A.ca_out_w = ca_out_w; A.ca_out_b = ca_out_b;
  A.ln1_g = ln1_g; A.ln1_b = ln1_b; A.ln2_g = ln2_g; A.ln2_b = ln2_b; A.ln3_g = ln3_g; A.ln3_b = ln3_b;
  A.ff1_w = ff1_w; A.ff1_b = ff1_b; A.ff2_w = ff2_w; A.ff2_b = ff2_b;
  A.vr_w = vr_w; A.vr_b = vr_b; A.vm_w = vm_w; A.vm_b = vm_b; A.obj_w = obj_w;
  A.Cm = Cm;
  A.pe = pe; A.emb = emb; A.kc = kc; A.vc = vc; A.mem = mem; A.vtmp = vtmp; A.cac = cac;
  A.q = q; A.u = u; A.hb = hb; A.w = wv; A.s = sbuf;
  A.out = (float*)d_out;
  A.bar = bar; A.flags = flags;

  void* params[1] = { &A };
  hipError_t e = hipLaunchCooperativeKernel((void*)decode_loop, dim3(NBLK), dim3(256), params, 0, stream);
  if (e != hipSuccess){
    decode_loop<<<dim3(NBLK), dim3(256), 0, stream>>>(A);
  }
}